// Round 12
// baseline (169.350 us; speedup 1.0000x reference)
//
#include <hip/hip_runtime.h>
#include <hip/hip_bf16.h>

#define NN 1024

typedef __attribute__((ext_vector_type(8))) short short8;     // 8 x bf16 MFMA frag
typedef __attribute__((ext_vector_type(4))) short short4e;    // 4 x bf16 packed store
typedef __attribute__((ext_vector_type(4))) float floatx4;
typedef __attribute__((ext_vector_type(4))) int intx4;

static __device__ __forceinline__ short bfb(float x) {
    return (short)__bfloat16_as_ushort(__float2bfloat16(x));
}

// ================= K1: Wh GEMM (8 waves, direct f32 W) + si/sj + aux prep =================
// grid = 512 wh + 8 pwb + 64 adjm = 584 blocks x 512 threads.
__global__ __launch_bounds__(512, 4) void wh_kernel(
    const float* __restrict__ h, const float* __restrict__ W,
    const float* __restrict__ a1, const float* __restrict__ a2,
    const float* __restrict__ proj_w, const int* __restrict__ adj,
    __hip_bfloat16* __restrict__ WhT,   // [B*H][64][NN] bf16
    float* __restrict__ si, float* __restrict__ sj,
    __hip_bfloat16* __restrict__ pwb,   // [256 o][256 k] bf16
    unsigned* __restrict__ adjm)        // [1024][32]
{
    int blk = blockIdx.x, t = threadIdx.x;

    if (blk >= 512) {
        if (blk < 520) {                 // pwb cast: 8 blocks x 512 t x 16 elems
            size_t base = (size_t)(blk - 512) * 8192 + (size_t)t * 16;
            #pragma unroll
            for (int k = 0; k < 16; k += 4) {
                floatx4 v = *(const floatx4*)(proj_w + base + k);
                short4e tmp;
                #pragma unroll
                for (int j = 0; j < 4; ++j) tmp[j] = bfb(v[j]);
                *(short4e*)(pwb + base + k) = tmp;
            }
        } else {                         // adjm: 64 blocks x 512 t x 1 word
            int idx = (blk - 520) * 512 + t;
            int n = idx >> 5, wd = idx & 31;
            const int* arow = adj + (size_t)n * NN + wd * 32;
            unsigned bits = 0;
            #pragma unroll
            for (int j4 = 0; j4 < 8; ++j4) {
                intx4 v = *(const intx4*)(arow + j4 * 4);
                #pragma unroll
                for (int j = 0; j < 4; ++j) if (v[j] != 0) bits |= (1u << (j4 * 4 + j));
            }
            adjm[(size_t)n * 32 + wd] = bits;
        }
        return;
    }

    // ---- wh main: 16 token rows, 8 waves; wave w owns col-tiles {w, w+8} ----
    int w = t >> 6, l = t & 63;
    int rl = l & 15, q = l >> 4;
    int r0 = blk * 16;
    int bb = r0 >> 10;
    int n0 = r0 & 1023;

    __shared__ float redsi[16][16];     // [tile][row]
    __shared__ float redsj[16][16];

    // A-frags: A[m=rl][k=q*8+j] from h rows (f32 -> bf16 in regs)
    short8 af[8];
    const float* Arow = h + (size_t)(r0 + rl) * 256 + q * 8;
    #pragma unroll
    for (int k0 = 0; k0 < 8; ++k0) {
        floatx4 v0 = *(const floatx4*)(Arow + k0 * 32);
        floatx4 v1 = *(const floatx4*)(Arow + k0 * 32 + 4);
        short8 a;
        #pragma unroll
        for (int j = 0; j < 4; ++j) { a[j] = bfb(v0[j]); a[j + 4] = bfb(v1[j]); }
        af[k0] = a;
    }

    #pragma unroll
    for (int j2 = 0; j2 < 2; ++j2) {
        int ct = w + j2 * 8;
        int hh = ct >> 2, ds = ct & 3;   // head, d-slice; d = ds*16 + rl
        const float* Wb = W + (size_t)hh * 16384 + ds * 16 + rl;

        floatx4 acc = {0.f, 0.f, 0.f, 0.f};
        #pragma unroll
        for (int k0 = 0; k0 < 8; ++k0) {
            short8 bfr;                  // B[k=q*8+jj][d-col=rl]
            #pragma unroll
            for (int jj = 0; jj < 8; ++jj)
                bfr[jj] = bfb(Wb[(size_t)(k0 * 32 + q * 8 + jj) * 64]);
            acc = __builtin_amdgcn_mfma_f32_16x16x32_bf16(af[k0], bfr, acc, 0, 0, 0);
        }

        short4e tmp;
        #pragma unroll
        for (int i = 0; i < 4; ++i) tmp[i] = bfb(acc[i]);
        *(short4e*)(WhT + ((size_t)(bb * 4 + hh) * 64 + ds * 16 + rl) * NN + n0 + q * 4) = tmp;

        float av1 = a1[hh * 64 + ds * 16 + rl];
        float av2 = a2[hh * 64 + ds * 16 + rl];
        #pragma unroll
        for (int i = 0; i < 4; ++i) {
            float p1 = acc[i] * av1;
            float p2 = acc[i] * av2;
            #pragma unroll
            for (int off = 1; off < 16; off <<= 1) {
                p1 += __shfl_xor(p1, off, 64);
                p2 += __shfl_xor(p2, off, 64);
            }
            if (rl == 0) { redsi[ct][q * 4 + i] = p1; redsj[ct][q * 4 + i] = p2; }
        }
    }
    __syncthreads();

    if (t < 64) {                        // si: head = t>>4, row = t&15
        int head = t >> 4, row = t & 15;
        float s = redsi[head * 4 + 0][row] + redsi[head * 4 + 1][row]
                + redsi[head * 4 + 2][row] + redsi[head * 4 + 3][row];
        si[(size_t)(bb * 4 + head) * NN + n0 + row] = s;
    } else if (t < 128) {
        int u = t - 64;
        int head = u >> 4, row = u & 15;
        float s = redsj[head * 4 + 0][row] + redsj[head * 4 + 1][row]
                + redsj[head * 4 + 2][row] + redsj[head * 4 + 3][row];
        sj[(size_t)(bb * 4 + head) * NN + n0 + row] = s;
    }
}

// ================= K2: attn (2 waves per head, split-m) + proj + LayerNorm =================
// grid = 512 blocks x 512 threads (8 waves). wave w: head = w>>1, m-half = w&1.
__global__ __launch_bounds__(512, 4) void attn_proj_kernel(
    const unsigned* __restrict__ adjm,
    const __hip_bfloat16* __restrict__ WhT,
    const float* __restrict__ si, const float* __restrict__ sj,
    const __hip_bfloat16* __restrict__ pwb,
    const float* __restrict__ h,
    const float* __restrict__ proj_b, const float* __restrict__ gamma,
    const float* __restrict__ beta,
    float* __restrict__ out)
{
    int blk = blockIdx.x, t = threadIdx.x;
    int w = t >> 6, l = t & 63;
    int rl = l & 15, q = l >> 4;
    int head = w >> 1, half = w & 1;
    int b = blk >> 6, n0 = (blk & 63) * 16;
    int bh = b * 4 + head;
    int r0 = blk * 16;

    __shared__ __align__(16) __hip_bfloat16 p_lds[8][16 * 136];   // per-wave p tile [16][128+8]
    __shared__ float hmf[2][16][260];    // [m-half][row][col] f32 head outputs (pre-merge)
    __shared__ float lpart[4][2][16];    // [head][half][row] partial softmax sums
    __shared__ float red[2][8][16];      // LN reductions

    int r = l >> 2, cg = l & 3;          // score roles: row r, m-window cg*32
    float sii = si[(size_t)bh * NN + n0 + r];
    const float* sjr = sj + (size_t)bh * NN;
    const unsigned* amrow = adjm + (size_t)(n0 + r) * 32;

    __hip_bfloat16* pt = &p_lds[w][0];
    const __hip_bfloat16* Ab = pt + rl * 136 + q * 8;
    const __hip_bfloat16* Bbase = WhT + ((size_t)bh * 64 + rl) * NN + q * 8;

    float lsum = 0.f;
    floatx4 acc[4] = { {0,0,0,0}, {0,0,0,0}, {0,0,0,0}, {0,0,0,0} };

    for (int itt = 0; itt < 4; ++itt) {
        int m0 = (half * 4 + itt) * 128;
        int mb = m0 + cg * 32;
        unsigned bits = amrow[mb >> 5];
        short8 pv_[4];
        #pragma unroll
        for (int c4 = 0; c4 < 8; ++c4) {
            floatx4 s4 = *(const floatx4*)(sjr + mb + c4 * 4);
            #pragma unroll
            for (int k = 0; k < 4; ++k) {
                float x = sii + s4[k];
                x = x > 0.f ? x : 0.2f * x;                       // leaky_relu 0.2
                x = ((bits >> (c4 * 4 + k)) & 1u) ? x : -1e9f;    // mask
                float pv = __expf(x);
                lsum += pv;
                pv_[c4 >> 1][(c4 & 1) * 4 + k] = bfb(pv);
            }
        }
        {   // wave-private LDS write (in-order DS per wave -> no barrier)
            short8* dst = (short8*)(pt + r * 136 + cg * 32);
            dst[0] = pv_[0]; dst[1] = pv_[1]; dst[2] = pv_[2]; dst[3] = pv_[3];
        }
        #pragma unroll
        for (int ks = 0; ks < 4; ++ks) {
            short8 afr = *(const short8*)(Ab + ks * 32);
            #pragma unroll
            for (int dt = 0; dt < 4; ++dt) {
                short8 bfr = *(const short8*)(Bbase + (size_t)dt * 16 * NN + m0 + ks * 32);
                acc[dt] = __builtin_amdgcn_mfma_f32_16x16x32_bf16(afr, bfr, acc[dt], 0, 0, 0);
            }
        }
    }

    // partial softmax sums: 4 lanes share a row
    lsum += __shfl_xor(lsum, 1, 64);
    lsum += __shfl_xor(lsum, 2, 64);
    if (cg == 0) lpart[head][half][r] = lsum;
    __syncthreads();

    // normalize + stage into per-half f32 buffers (merged at proj A-load)
    float riv[4];
    #pragma unroll
    for (int i = 0; i < 4; ++i) {
        int row = q * 4 + i;
        riv[i] = 1.f / (lpart[head][0][row] + lpart[head][1][row]);
    }
    #pragma unroll
    for (int dt = 0; dt < 4; ++dt) {
        #pragma unroll
        for (int i = 0; i < 4; ++i)
            hmf[half][q * 4 + i][head * 64 + dt * 16 + rl] = acc[dt][i] * riv[i];
    }
    __syncthreads();

    // ---- proj: A = bf16(hmf[0]+hmf[1]); wave w takes col-tiles {w, w+8} ----
    short8 paf[8];
    #pragma unroll
    for (int k0 = 0; k0 < 8; ++k0) {
        const float* h0 = &hmf[0][rl][k0 * 32 + q * 8];
        const float* h1 = &hmf[1][rl][k0 * 32 + q * 8];
        floatx4 a0 = *(const floatx4*)h0, a1v = *(const floatx4*)(h0 + 4);
        floatx4 b0 = *(const floatx4*)h1, b1v = *(const floatx4*)(h1 + 4);
        short8 a;
        #pragma unroll
        for (int j = 0; j < 4; ++j) { a[j] = bfb(a0[j] + b0[j]); a[j + 4] = bfb(a1v[j] + b1v[j]); }
        paf[k0] = a;
    }

    floatx4 pacc[2];
    #pragma unroll
    for (int j2 = 0; j2 < 2; ++j2) {
        int ct = w + j2 * 8;
        const __hip_bfloat16* Brow = pwb + (size_t)(ct * 16 + rl) * 256 + q * 8;
        floatx4 a = {0.f, 0.f, 0.f, 0.f};
        #pragma unroll
        for (int k0 = 0; k0 < 8; ++k0) {
            short8 bfr = *(const short8*)(Brow + k0 * 32);
            a = __builtin_amdgcn_mfma_f32_16x16x32_bf16(paf[k0], bfr, a, 0, 0, 0);
        }
        pacc[j2] = a;
    }

    // bias + residual + LayerNorm (rows q*4+i, this wave's cols: (w+8*j2)*16+rl)
    float ps[4] = {0.f, 0.f, 0.f, 0.f};
    #pragma unroll
    for (int j2 = 0; j2 < 2; ++j2) {
        int col = (w + j2 * 8) * 16 + rl;
        float pb = proj_b[col];
        #pragma unroll
        for (int i = 0; i < 4; ++i) {
            float v = pacc[j2][i] + pb + h[(size_t)(r0 + q * 4 + i) * 256 + col];
            pacc[j2][i] = v;
            ps[i] += v;
        }
    }
    #pragma unroll
    for (int i = 0; i < 4; ++i) {
        float s = ps[i];
        #pragma unroll
        for (int off = 1; off < 16; off <<= 1) s += __shfl_xor(s, off, 64);
        ps[i] = s;
    }
    if (rl == 0) {
        for (int i = 0; i < 4; ++i) red[0][w][q * 4 + i] = ps[i];
    }
    __syncthreads();
    float mu[4];
    #pragma unroll
    for (int i = 0; i < 4; ++i) {
        int row = q * 4 + i;
        float s = 0.f;
        #pragma unroll
        for (int w2 = 0; w2 < 8; ++w2) s += red[0][w2][row];
        mu[i] = s * (1.f / 256.f);
    }

    float vs[4] = {0.f, 0.f, 0.f, 0.f};
    #pragma unroll
    for (int j2 = 0; j2 < 2; ++j2) {
        #pragma unroll
        for (int i = 0; i < 4; ++i) { float cv = pacc[j2][i] - mu[i]; vs[i] += cv * cv; }
    }
    #pragma unroll
    for (int i = 0; i < 4; ++i) {
        float s = vs[i];
        #pragma unroll
        for (int off = 1; off < 16; off <<= 1) s += __shfl_xor(s, off, 64);
        vs[i] = s;
    }
    if (rl == 0) {
        for (int i = 0; i < 4; ++i) red[1][w][q * 4 + i] = vs[i];
    }
    __syncthreads();
    float rs[4];
    #pragma unroll
    for (int i = 0; i < 4; ++i) {
        int row = q * 4 + i;
        float s = 0.f;
        #pragma unroll
        for (int w2 = 0; w2 < 8; ++w2) s += red[1][w2][row];
        rs[i] = rsqrtf(s * (1.f / 256.f) + 1e-5f);
    }
    #pragma unroll
    for (int j2 = 0; j2 < 2; ++j2) {
        int col = (w + j2 * 8) * 16 + rl;
        float g = gamma[col], be = beta[col];
        #pragma unroll
        for (int i = 0; i < 4; ++i)
            out[(size_t)(r0 + q * 4 + i) * 256 + col] = (pacc[j2][i] - mu[i]) * rs[i] * g + be;
    }
}

extern "C" void kernel_launch(void* const* d_in, const int* in_sizes, int n_in,
                              void* d_out, int out_size, void* d_ws, size_t ws_size,
                              hipStream_t stream) {
    const float* h      = (const float*)d_in[0];
    const int*   adj    = (const int*)d_in[1];
    const float* W      = (const float*)d_in[2];
    const float* a1     = (const float*)d_in[3];
    const float* a2     = (const float*)d_in[4];
    const float* proj_w = (const float*)d_in[5];
    const float* proj_b = (const float*)d_in[6];
    const float* gamma  = (const float*)d_in[7];
    const float* beta   = (const float*)d_in[8];
    float* out = (float*)d_out;

    char* ws = (char*)d_ws;
    __hip_bfloat16* WhT = (__hip_bfloat16*)ws;   ws += (size_t)32 * 64 * NN * 2;   // 4 MB
    __hip_bfloat16* pwb = (__hip_bfloat16*)ws;   ws += 256 * 256 * 2;              // 128 KB
    float* si = (float*)ws;                      ws += (size_t)32 * NN * 4;        // 128 KB
    float* sj = (float*)ws;                      ws += (size_t)32 * NN * 4;        // 128 KB
    unsigned* adjm = (unsigned*)ws;              ws += (size_t)NN * 32 * 4;        // 128 KB

    wh_kernel<<<584, 512, 0, stream>>>(h, W, a1, a2, proj_w, adj, WhT, si, sj, pwb, adjm);
    attn_proj_kernel<<<512, 512, 0, stream>>>(adjm, WhT, si, sj, pwb, h, proj_b, gamma, beta, out);
}

// Round 13
// 125.189 us; speedup vs baseline: 1.3527x; 1.3527x over previous
//
#include <hip/hip_runtime.h>
#include <hip/hip_bf16.h>

#define NN 1024
#define LOG2E 1.44269504088896f

typedef __attribute__((ext_vector_type(8))) short short8;
typedef __attribute__((ext_vector_type(4))) short short4e;
typedef __attribute__((ext_vector_type(4))) float floatx4;
typedef __attribute__((ext_vector_type(4))) int intx4;
typedef __attribute__((ext_vector_type(2))) int intx2;

// fast f32->bf16 (round-half-up) pack of two floats into one dword
static __device__ __forceinline__ unsigned pk2(float f0, float f1) {
    unsigned u0 = __float_as_uint(f0) + 0x8000u;
    unsigned u1 = __float_as_uint(f1) + 0x8000u;
    return __builtin_amdgcn_perm(u1, u0, 0x07060302u);   // [u1.hi16 : u0.hi16]
}
static __device__ __forceinline__ short8 pk8(floatx4 v0, floatx4 v1) {
    union { intx4 i; short8 s; } u;
    u.i[0] = (int)pk2(v0[0], v0[1]); u.i[1] = (int)pk2(v0[2], v0[3]);
    u.i[2] = (int)pk2(v1[0], v1[1]); u.i[3] = (int)pk2(v1[2], v1[3]);
    return u.s;
}

// ================= K0: prep — WTb transpose, pwb cast, adj bitmask =================
// grid = 16 + 16 + 128 = 160 blocks x 256 threads
__global__ __launch_bounds__(256) void prep_kernel(
    const float* __restrict__ W, const float* __restrict__ proj_w,
    const int* __restrict__ adj,
    __hip_bfloat16* __restrict__ WTb,    // [256 o][256 k], o = hh*64+d
    __hip_bfloat16* __restrict__ pwb,    // [256 o][256 k]
    unsigned* __restrict__ adjm)         // [1024][32]
{
    int blk = blockIdx.x, t = threadIdx.x;
    if (blk < 16) {
        int o = blk * 16 + (t >> 4);
        int hh = o >> 6, d = o & 63;
        #pragma unroll
        for (int kk = 0; kk < 16; ++kk) {
            int k = (t & 15) + 16 * kk;
            WTb[(size_t)o * 256 + k] = __float2bfloat16(W[((size_t)hh * 256 + k) * 64 + d]);
        }
    } else if (blk < 32) {
        size_t base = (size_t)(blk - 16) * 4096 + (size_t)t * 16;
        #pragma unroll
        for (int k = 0; k < 16; k += 8) {
            floatx4 v0 = *(const floatx4*)(proj_w + base + k);
            floatx4 v1 = *(const floatx4*)(proj_w + base + k + 4);
            *(short8*)(pwb + base + k) = pk8(v0, v1);
        }
    } else {
        int n = (blk - 32) * 8 + (t >> 5);
        int wd = t & 31;
        const int* arow = adj + (size_t)n * NN + wd * 32;
        unsigned bits = 0;
        #pragma unroll
        for (int j4 = 0; j4 < 8; ++j4) {
            intx4 v = *(const intx4*)(arow + j4 * 4);
            #pragma unroll
            for (int j = 0; j < 4; ++j) if (v[j] != 0) bits |= (1u << (j4 * 4 + j));
        }
        adjm[(size_t)n * 32 + wd] = bits;
    }
}

// ================= K1: Wh GEMM — B streamed via wave-private LDS, reg prefetch =================
// grid = 512 blocks x 256t (4 waves). Wave w = d-slice w; tile j = head j (ct = w + 4j).
__global__ __launch_bounds__(256) void wh_kernel(
    const float* __restrict__ h,
    const __hip_bfloat16* __restrict__ WTb,
    const float* __restrict__ a1, const float* __restrict__ a2,
    __hip_bfloat16* __restrict__ WhT,   // [B*H][64][NN]
    float* __restrict__ si, float* __restrict__ sj)   // PRESCALED by log2e
{
    int t = threadIdx.x;
    int w = t >> 6, l = t & 63;
    int rl = l & 15, q = l >> 4;
    int r0 = blockIdx.x * 16;
    int bb = r0 >> 10, n0 = r0 & 1023;

    __shared__ __align__(16) __hip_bfloat16 bst[4][16][264];  // wave-private B tile 16x256 (+8 pad)
    __shared__ float redsi[4][4][16];   // [slice][head][row]
    __shared__ float redsj[4][4][16];

    // A-frags from h (f32 -> bf16 pack)
    short8 af[8];
    const float* Arow = h + (size_t)(r0 + rl) * 256 + q * 8;
    #pragma unroll
    for (int k0 = 0; k0 < 8; ++k0) {
        floatx4 v0 = *(const floatx4*)(Arow + k0 * 32);
        floatx4 v1 = *(const floatx4*)(Arow + k0 * 32 + 4);
        af[k0] = pk8(v0, v1);
    }

    // stage tile j=0 (ct = w): 8KB, coalesced: inst k -> elem k*512 + l*8
    short8 sreg[8], nreg[8];
    {
        const __hip_bfloat16* src = WTb + (size_t)w * 16 * 256;
        #pragma unroll
        for (int k = 0; k < 8; ++k) sreg[k] = *(const short8*)(src + k * 512 + l * 8);
    }

    #pragma unroll
    for (int j = 0; j < 4; ++j) {       // ct = w + 4j -> head j, d-slice w
        if (j < 3) {
            const __hip_bfloat16* src = WTb + (size_t)(w + 4 * (j + 1)) * 16 * 256;
            #pragma unroll
            for (int k = 0; k < 8; ++k) nreg[k] = *(const short8*)(src + k * 512 + l * 8);
        }
        // ds_write own buffer (rows k*2 + (l>>5), cols (l&31)*8)
        #pragma unroll
        for (int k = 0; k < 8; ++k)
            *(short8*)(&bst[w][k * 2 + (l >> 5)][(l & 31) * 8]) = sreg[k];
        // frags + MFMA (same-wave DS is in-order: reads see writes)
        floatx4 acc = {0.f, 0.f, 0.f, 0.f};
        #pragma unroll
        for (int k0 = 0; k0 < 8; ++k0) {
            short8 bf = *(const short8*)(&bst[w][rl][q * 8 + k0 * 32]);
            acc = __builtin_amdgcn_mfma_f32_16x16x32_bf16(af[k0], bf, acc, 0, 0, 0);
        }

        // WhT[bh = bb*4+j][d = w*16+rl][n = n0+q*4 ..]
        intx2 pr;
        pr[0] = (int)pk2(acc[0], acc[1]);
        pr[1] = (int)pk2(acc[2], acc[3]);
        *(intx2*)(WhT + ((size_t)(bb * 4 + j) * 64 + w * 16 + rl) * NN + n0 + q * 4) = pr;

        // si/sj partials (prescaled by log2e), reduce over this wave's 16 d's
        float av1 = a1[j * 64 + w * 16 + rl] * LOG2E;
        float av2 = a2[j * 64 + w * 16 + rl] * LOG2E;
        #pragma unroll
        for (int i = 0; i < 4; ++i) {
            float p1 = acc[i] * av1, p2 = acc[i] * av2;
            #pragma unroll
            for (int off = 1; off < 16; off <<= 1) {
                p1 += __shfl_xor(p1, off, 64);
                p2 += __shfl_xor(p2, off, 64);
            }
            if (rl == 0) { redsi[w][j][q * 4 + i] = p1; redsj[w][j][q * 4 + i] = p2; }
        }
        #pragma unroll
        for (int z = 0; z < 8; ++z) sreg[z] = nreg[z];
    }
    __syncthreads();

    if (t < 64) {
        int head = t >> 4, row = t & 15;
        si[(size_t)(bb * 4 + head) * NN + n0 + row] =
            redsi[0][head][row] + redsi[1][head][row] + redsi[2][head][row] + redsi[3][head][row];
    } else if (t < 128) {
        int u = t - 64;
        int head = u >> 4, row = u & 15;
        sj[(size_t)(bb * 4 + head) * NN + n0 + row] =
            redsj[0][head][row] + redsj[1][head][row] + redsj[2][head][row] + redsj[3][head][row];
    }
}

// ================= K2: attn — wave = head, barrier-free m-loop, LDS-staged B =================
// grid = 512 blocks x 256t. Block = (b, n-tile of 16); wave w = head w. TM = 64.
__global__ __launch_bounds__(256) void attn_kernel(
    const unsigned* __restrict__ adjm,
    const __hip_bfloat16* __restrict__ WhT,
    const float* __restrict__ si, const float* __restrict__ sj,
    __hip_bfloat16* __restrict__ hmb)   // [B*N][256]
{
    int bx = blockIdx.x, t = threadIdx.x;
    int w = t >> 6, l = t & 63;
    int rl = l & 15, q = l >> 4;
    int b = bx >> 6, n0 = (bx & 63) * 16;
    int bh = b * 4 + w;

    __shared__ __align__(16) __hip_bfloat16 bst[4][64][72];    // wave-private: 64 d x 64 m (+8 pad)
    __shared__ __align__(16) __hip_bfloat16 p_lds[4][16][72];  // wave-private: 16 rows x 64 m
    __shared__ float rinvs[4][16];

    int r = l >> 2, cg = l & 3;          // score roles: row r, 16-entry chunk cg
    float sii = si[(size_t)bh * NN + n0 + r];
    const float* sjr = sj + (size_t)bh * NN;
    const unsigned* amrow = adjm + (size_t)(n0 + r) * 32;

    float lsum = 0.f;
    floatx4 acc[4] = { {0,0,0,0}, {0,0,0,0}, {0,0,0,0}, {0,0,0,0} };

    const __hip_bfloat16* Bsrc = WhT + (size_t)bh * 64 * NN;

    // stage tile 0: 8KB = 64 d x 64 m; inst k: row k*8 + (l>>3), col (l&7)*8
    short8 sreg[8], nreg[8];
    #pragma unroll
    for (int k = 0; k < 8; ++k)
        sreg[k] = *(const short8*)(Bsrc + (size_t)(k * 8 + (l >> 3)) * NN + (l & 7) * 8);

    #pragma unroll
    for (int it = 0; it < 16; ++it) {
        int m0 = it * 64;
        if (it < 15) {
            int m1 = m0 + 64;
            #pragma unroll
            for (int k = 0; k < 8; ++k)
                nreg[k] = *(const short8*)(Bsrc + (size_t)(k * 8 + (l >> 3)) * NN + m1 + (l & 7) * 8);
        }
        // ---- scores for this wave's 16 rows x 64 m (16 entries/lane) ----
        {
            int mb = m0 + cg * 16;
            unsigned bits = amrow[(m0 >> 5) + (cg >> 1)] >> ((cg & 1) * 16);
            unsigned pkd[4];
            #pragma unroll
            for (int c4 = 0; c4 < 4; ++c4) {
                floatx4 s4 = *(const floatx4*)(sjr + mb + c4 * 4);
                float pv[4];
                #pragma unroll
                for (int k = 0; k < 4; ++k) {
                    float x = sii + s4[k];
                    x = fmaxf(x, 0.2f * x);                               // leaky (prescaled)
                    x = ((bits >> (c4 * 4 + k)) & 1u) ? x : -1e9f;        // mask -> exp2 = 0
                    pv[k] = exp2f(x);
                    lsum += pv[k];
                }
                pkd[c4] = 0;  // placeholder, packed below
                pkd[c4] = (unsigned)pk2(pv[0], pv[1]) | 0u;               // low pair
                // store both pairs: build two dwords per c4? -> handled below
                // (we pack 4 entries into 2 dwords)
                unsigned hi = pk2(pv[2], pv[3]);
                // write 8B at row r, col mb-m0 + c4*4
                intx2 two; two[0] = (int)pkd[c4]; two[1] = (int)hi;
                *(intx2*)(&p_lds[w][r][cg * 16 + c4 * 4]) = two;
            }
        }
        // ---- ds_write B tile (waits only on sreg's loads; nreg stays in flight) ----
        #pragma unroll
        for (int k = 0; k < 8; ++k)
            *(short8*)(&bst[w][k * 8 + (l >> 3)][(l & 7) * 8]) = sreg[k];
        // ---- MFMA: A = p rows, B = d-slices; 4 dt x 2 ks ----
        #pragma unroll
        for (int ks = 0; ks < 2; ++ks) {
            short8 afr = *(const short8*)(&p_lds[w][rl][q * 8 + ks * 32]);
            #pragma unroll
            for (int dt = 0; dt < 4; ++dt) {
                short8 bfr = *(const short8*)(&bst[w][dt * 16 + rl][q * 8 + ks * 32]);
                acc[dt] = __builtin_amdgcn_mfma_f32_16x16x32_bf16(afr, bfr, acc[dt], 0, 0, 0);
            }
        }
        #pragma unroll
        for (int z = 0; z < 8; ++z) sreg[z] = nreg[z];
    }

    // softmax denominators: reduce over 4 lanes sharing row r
    lsum += __shfl_xor(lsum, 1, 64);
    lsum += __shfl_xor(lsum, 2, 64);
    if (cg == 0) rinvs[w][r] = 1.f / lsum;
    float riv[4];
    #pragma unroll
    for (int i = 0; i < 4; ++i) riv[i] = rinvs[w][q * 4 + i];   // same-wave LDS

    // store hmb rows n0+q*4+i, cols w*64 + dt*16 + rl
    #pragma unroll
    for (int dt = 0; dt < 4; ++dt) {
        #pragma unroll
        for (int i = 0; i < 4; ++i) {
            float v = acc[dt][i] * riv[i];
            unsigned uv = (__float_as_uint(v) + 0x8000u) >> 16;
            hmb[((size_t)(b * NN) + n0 + q * 4 + i) * 256 + w * 64 + dt * 16 + rl] =
                __ushort_as_bfloat16((unsigned short)uv);
        }
    }
}

// ================= K3: proj — B streamed via wave-private LDS + bias + residual + LN =================
// grid = 512 blocks x 256t; wave w tiles ct = w + 4j.
__global__ __launch_bounds__(256) void proj_ln_kernel(
    const __hip_bfloat16* __restrict__ hmb,
    const float* __restrict__ h,
    const __hip_bfloat16* __restrict__ pwb,
    const float* __restrict__ proj_b, const float* __restrict__ gamma,
    const float* __restrict__ beta,
    float* __restrict__ out)
{
    int t = threadIdx.x;
    int w = t >> 6, l = t & 63;
    int rl = l & 15, q = l >> 4;
    int r0 = blockIdx.x * 16;

    __shared__ __align__(16) __hip_bfloat16 bst[4][16][264];
    __shared__ float red[2][4][16];

    short8 af[8];
    const __hip_bfloat16* Arow = hmb + (size_t)(r0 + rl) * 256 + q * 8;
    #pragma unroll
    for (int k0 = 0; k0 < 8; ++k0) af[k0] = *(const short8*)(Arow + k0 * 32);

    short8 sreg[8], nreg[8];
    {
        const __hip_bfloat16* src = pwb + (size_t)w * 16 * 256;
        #pragma unroll
        for (int k = 0; k < 8; ++k) sreg[k] = *(const short8*)(src + k * 512 + l * 8);
    }

    floatx4 pacc[4];
    #pragma unroll
    for (int j = 0; j < 4; ++j) {
        if (j < 3) {
            const __hip_bfloat16* src = pwb + (size_t)(w + 4 * (j + 1)) * 16 * 256;
            #pragma unroll
            for (int k = 0; k < 8; ++k) nreg[k] = *(const short8*)(src + k * 512 + l * 8);
        }
        #pragma unroll
        for (int k = 0; k < 8; ++k)
            *(short8*)(&bst[w][k * 2 + (l >> 5)][(l & 31) * 8]) = sreg[k];
        floatx4 a = {0.f, 0.f, 0.f, 0.f};
        #pragma unroll
        for (int k0 = 0; k0 < 8; ++k0) {
            short8 bf = *(const short8*)(&bst[w][rl][q * 8 + k0 * 32]);
            a = __builtin_amdgcn_mfma_f32_16x16x32_bf16(af[k0], bf, a, 0, 0, 0);
        }
        pacc[j] = a;
        #pragma unroll
        for (int z = 0; z < 8; ++z) sreg[z] = nreg[z];
    }

    // bias + residual + LayerNorm
    float ps[4] = {0.f, 0.f, 0.f, 0.f};
    #pragma unroll
    for (int j = 0; j < 4; ++j) {
        int col = (w + j * 4) * 16 + rl;
        float pb = proj_b[col];
        #pragma unroll
        for (int i = 0; i < 4; ++i) {
            float v = pacc[j][i] + pb + h[(size_t)(r0 + q * 4 + i) * 256 + col];
            pacc[j][i] = v;
            ps[i] += v;
        }
    }
    #pragma unroll
    for (int i = 0; i < 4; ++i) {
        float s = ps[i];
        #pragma unroll
        for (int off = 1; off < 16; off <<= 1) s += __shfl_xor(s, off, 64);
        ps[i] = s;
    }
    if (rl == 0) {
        for (int i = 0; i < 4; ++i) red[0][w][q * 4 + i] = ps[i];
    }
    __syncthreads();
    float mu[4];
    #pragma unroll
    for (int i = 0; i < 4; ++i) {
        int row = q * 4 + i;
        mu[i] = (red[0][0][row] + red[0][1][row] + red[0][2][row] + red[0][3][row]) * (1.f / 256.f);
    }
    float vs[4] = {0.f, 0.f, 0.f, 0.f};
    #pragma unroll
    for (int j = 0; j < 4; ++j) {
        #pragma unroll
        for (int i = 0; i < 4; ++i) { float cv = pacc[j][i] - mu[i]; vs[i] += cv * cv; }
    }
    #pragma unroll
    for (int i = 0; i < 4; ++i) {
        float s = vs[i];
        #pragma unroll
        for (int off = 1; off < 16; off <<= 1) s += __shfl_xor(s, off, 64);
        vs[i] = s;
    }
    if (rl == 0) {
        for (int i = 0; i < 4; ++i) red[1][w][q * 4 + i] = vs[i];
    }
    __syncthreads();
    float rs[4];
    #pragma unroll
    for (int i = 0; i < 4; ++i) {
        int row = q * 4 + i;
        float var = (red[1][0][row] + red[1][1][row] + red[1][2][row] + red[1][3][row]) * (1.f / 256.f);
        rs[i] = rsqrtf(var + 1e-5f);
    }
    #pragma unroll
    for (int j = 0; j < 4; ++j) {
        int col = (w + j * 4) * 16 + rl;
        float g = gamma[col], be = beta[col];
        #pragma unroll
        for (int i = 0; i < 4; ++i)
            out[(size_t)(r0 + q * 4 + i) * 256 + col] = (pacc[j][i] - mu[i]) * rs[i] * g + be;
    }
}

extern "C" void kernel_launch(void* const* d_in, const int* in_sizes, int n_in,
                              void* d_out, int out_size, void* d_ws, size_t ws_size,
                              hipStream_t stream) {
    const float* h      = (const float*)d_in[0];
    const int*   adj    = (const int*)d_in[1];
    const float* W      = (const float*)d_in[2];
    const float* a1     = (const float*)d_in[3];
    const float* a2     = (const float*)d_in[4];
    const float* proj_w = (const float*)d_in[5];
    const float* proj_b = (const float*)d_in[6];
    const float* gamma  = (const float*)d_in[7];
    const float* beta   = (const float*)d_in[8];
    float* out = (float*)d_out;

    char* ws = (char*)d_ws;
    __hip_bfloat16* WhT = (__hip_bfloat16*)ws;   ws += (size_t)32 * 64 * NN * 2;   // 4 MB
    __hip_bfloat16* hmb = (__hip_bfloat16*)ws;   ws += (size_t)8 * NN * 256 * 2;   // 4 MB
    __hip_bfloat16* WTb = (__hip_bfloat16*)ws;   ws += 256 * 256 * 2;              // 128 KB
    __hip_bfloat16* pwb = (__hip_bfloat16*)ws;   ws += 256 * 256 * 2;              // 128 KB
    float* si = (float*)ws;                      ws += (size_t)32 * NN * 4;        // 128 KB
    float* sj = (float*)ws;                      ws += (size_t)32 * NN * 4;        // 128 KB
    unsigned* adjm = (unsigned*)ws;              ws += (size_t)NN * 32 * 4;        // 128 KB

    prep_kernel<<<160, 256, 0, stream>>>(W, proj_w, adj, WTb, pwb, adjm);
    wh_kernel<<<512, 256, 0, stream>>>(h, WTb, a1, a2, WhT, si, sj);
    attn_kernel<<<512, 256, 0, stream>>>(adjm, WhT, si, sj, hmb);
    proj_ln_kernel<<<512, 256, 0, stream>>>(hmb, h, pwb, proj_b, gamma, beta, out);
}

// Round 14
// 122.069 us; speedup vs baseline: 1.3873x; 1.0256x over previous
//
#include <hip/hip_runtime.h>
#include <hip/hip_bf16.h>

#define NN 1024
#define LOG2E 1.44269504088896f

typedef __attribute__((ext_vector_type(8))) short short8;
typedef __attribute__((ext_vector_type(4))) short short4e;
typedef __attribute__((ext_vector_type(4))) float floatx4;
typedef __attribute__((ext_vector_type(4))) int intx4;
typedef __attribute__((ext_vector_type(2))) int intx2;

// fast f32->bf16 (round-half-up) pack of two floats into one dword
static __device__ __forceinline__ unsigned pk2(float f0, float f1) {
    unsigned u0 = __float_as_uint(f0) + 0x8000u;
    unsigned u1 = __float_as_uint(f1) + 0x8000u;
    return __builtin_amdgcn_perm(u1, u0, 0x07060302u);   // [u1.hi16 : u0.hi16]
}
static __device__ __forceinline__ short8 pk8(floatx4 v0, floatx4 v1) {
    union { intx4 i; short8 s; } u;
    u.i[0] = (int)pk2(v0[0], v0[1]); u.i[1] = (int)pk2(v0[2], v0[3]);
    u.i[2] = (int)pk2(v1[0], v1[1]); u.i[3] = (int)pk2(v1[2], v1[3]);
    return u.s;
}

// ================= K0: prep — WTb transpose, pwb cast, adj bitmask =================
// grid = 16 + 16 + 128 = 160 blocks x 256 threads
__global__ __launch_bounds__(256) void prep_kernel(
    const float* __restrict__ W, const float* __restrict__ proj_w,
    const int* __restrict__ adj,
    __hip_bfloat16* __restrict__ WTb,    // [256 o][256 k], o = hh*64+d
    __hip_bfloat16* __restrict__ pwb,    // [256 o][256 k]
    unsigned* __restrict__ adjm)         // [1024][32]
{
    int blk = blockIdx.x, t = threadIdx.x;
    if (blk < 16) {
        int o = blk * 16 + (t >> 4);
        int hh = o >> 6, d = o & 63;
        #pragma unroll
        for (int kk = 0; kk < 16; ++kk) {
            int k = (t & 15) + 16 * kk;
            WTb[(size_t)o * 256 + k] = __float2bfloat16(W[((size_t)hh * 256 + k) * 64 + d]);
        }
    } else if (blk < 32) {
        size_t base = (size_t)(blk - 16) * 4096 + (size_t)t * 16;
        #pragma unroll
        for (int k = 0; k < 16; k += 8) {
            floatx4 v0 = *(const floatx4*)(proj_w + base + k);
            floatx4 v1 = *(const floatx4*)(proj_w + base + k + 4);
            *(short8*)(pwb + base + k) = pk8(v0, v1);
        }
    } else {
        int n = (blk - 32) * 8 + (t >> 5);
        int wd = t & 31;
        const int* arow = adj + (size_t)n * NN + wd * 32;
        unsigned bits = 0;
        #pragma unroll
        for (int j4 = 0; j4 < 8; ++j4) {
            intx4 v = *(const intx4*)(arow + j4 * 4);
            #pragma unroll
            for (int j = 0; j < 4; ++j) if (v[j] != 0) bits |= (1u << (j4 * 4 + j));
        }
        adjm[(size_t)n * 32 + wd] = bits;
    }
}

// ================= K1: Wh GEMM — B streamed via wave-private LDS, reg prefetch =================
// grid = 512 blocks x 256t (4 waves). Wave w = d-slice w; tile j = head j (ct = w + 4j).
__global__ __launch_bounds__(256) void wh_kernel(
    const float* __restrict__ h,
    const __hip_bfloat16* __restrict__ WTb,
    const float* __restrict__ a1, const float* __restrict__ a2,
    __hip_bfloat16* __restrict__ WhT,   // [B*H][64][NN]
    float* __restrict__ si, float* __restrict__ sj)   // PRESCALED by log2e
{
    int t = threadIdx.x;
    int w = t >> 6, l = t & 63;
    int rl = l & 15, q = l >> 4;
    int r0 = blockIdx.x * 16;
    int bb = r0 >> 10, n0 = r0 & 1023;

    __shared__ __align__(16) __hip_bfloat16 bst[4][16][264];  // wave-private B tile 16x256 (+8 pad)
    __shared__ float redsi[4][4][16];   // [slice][head][row]
    __shared__ float redsj[4][4][16];

    // A-frags from h (f32 -> bf16 pack)
    short8 af[8];
    const float* Arow = h + (size_t)(r0 + rl) * 256 + q * 8;
    #pragma unroll
    for (int k0 = 0; k0 < 8; ++k0) {
        floatx4 v0 = *(const floatx4*)(Arow + k0 * 32);
        floatx4 v1 = *(const floatx4*)(Arow + k0 * 32 + 4);
        af[k0] = pk8(v0, v1);
    }

    // stage tile j=0 (ct = w): 8KB, coalesced: inst k -> elem k*512 + l*8
    short8 sreg[8], nreg[8];
    {
        const __hip_bfloat16* src = WTb + (size_t)w * 16 * 256;
        #pragma unroll
        for (int k = 0; k < 8; ++k) sreg[k] = *(const short8*)(src + k * 512 + l * 8);
    }

    #pragma unroll
    for (int j = 0; j < 4; ++j) {       // ct = w + 4j -> head j, d-slice w
        if (j < 3) {
            const __hip_bfloat16* src = WTb + (size_t)(w + 4 * (j + 1)) * 16 * 256;
            #pragma unroll
            for (int k = 0; k < 8; ++k) nreg[k] = *(const short8*)(src + k * 512 + l * 8);
        }
        // ds_write own buffer (rows k*2 + (l>>5), cols (l&31)*8)
        #pragma unroll
        for (int k = 0; k < 8; ++k)
            *(short8*)(&bst[w][k * 2 + (l >> 5)][(l & 31) * 8]) = sreg[k];
        // frags + MFMA (same-wave DS is in-order: reads see writes)
        floatx4 acc = {0.f, 0.f, 0.f, 0.f};
        #pragma unroll
        for (int k0 = 0; k0 < 8; ++k0) {
            short8 bf = *(const short8*)(&bst[w][rl][q * 8 + k0 * 32]);
            acc = __builtin_amdgcn_mfma_f32_16x16x32_bf16(af[k0], bf, acc, 0, 0, 0);
        }

        // WhT[bh = bb*4+j][d = w*16+rl][n = n0+q*4 ..]
        intx2 pr;
        pr[0] = (int)pk2(acc[0], acc[1]);
        pr[1] = (int)pk2(acc[2], acc[3]);
        *(intx2*)(WhT + ((size_t)(bb * 4 + j) * 64 + w * 16 + rl) * NN + n0 + q * 4) = pr;

        // si/sj partials (prescaled by log2e), reduce over this wave's 16 d's
        float av1 = a1[j * 64 + w * 16 + rl] * LOG2E;
        float av2 = a2[j * 64 + w * 16 + rl] * LOG2E;
        #pragma unroll
        for (int i = 0; i < 4; ++i) {
            float p1 = acc[i] * av1, p2 = acc[i] * av2;
            #pragma unroll
            for (int off = 1; off < 16; off <<= 1) {
                p1 += __shfl_xor(p1, off, 64);
                p2 += __shfl_xor(p2, off, 64);
            }
            if (rl == 0) { redsi[w][j][q * 4 + i] = p1; redsj[w][j][q * 4 + i] = p2; }
        }
        #pragma unroll
        for (int z = 0; z < 8; ++z) sreg[z] = nreg[z];
    }
    __syncthreads();

    if (t < 64) {
        int head = t >> 4, row = t & 15;
        si[(size_t)(bb * 4 + head) * NN + n0 + row] =
            redsi[0][head][row] + redsi[1][head][row] + redsi[2][head][row] + redsi[3][head][row];
    } else if (t < 128) {
        int u = t - 64;
        int head = u >> 4, row = u & 15;
        sj[(size_t)(bb * 4 + head) * NN + n0 + row] =
            redsj[0][head][row] + redsj[1][head][row] + redsj[2][head][row] + redsj[3][head][row];
    }
}

// ================= K2: attn (R13 structure) + proj + LN fused, LDS overlaid =================
// grid = 512 blocks x 256t. Block = (b, 16-token tile); wave w = head w in attn phase.
// LDS plan (46592 B): [attn] bst 4x64x72 @0 | p_lds 4x16x72 @36864 | rinvs @46080
//                     [proj] pbst 4x16x264 @0 | hm 16x264 @36864 | red @45312
__global__ __launch_bounds__(256) void attn_proj_kernel(
    const unsigned* __restrict__ adjm,
    const __hip_bfloat16* __restrict__ WhT,
    const float* __restrict__ si, const float* __restrict__ sj,
    const __hip_bfloat16* __restrict__ pwb,
    const float* __restrict__ h,
    const float* __restrict__ proj_b, const float* __restrict__ gamma,
    const float* __restrict__ beta,
    float* __restrict__ out)
{
    __shared__ __align__(16) char smem[46592];
    auto bst   = reinterpret_cast<__hip_bfloat16 (*)[64][72]>(smem);          // attn B tiles
    auto pl    = reinterpret_cast<__hip_bfloat16 (*)[16][72]>(smem + 36864);  // attn p tiles
    auto rinvs = reinterpret_cast<float (*)[16]>(smem + 46080);
    auto pbst  = reinterpret_cast<__hip_bfloat16 (*)[16][264]>(smem);         // proj B tiles
    auto hm    = reinterpret_cast<__hip_bfloat16 (*)[264]>(smem + 36864);     // head outputs
    auto red   = reinterpret_cast<float (*)[4][16]>(smem + 45312);            // LN reductions

    int bx = blockIdx.x, t = threadIdx.x;
    int w = t >> 6, l = t & 63;
    int rl = l & 15, q = l >> 4;
    int b = bx >> 6, n0 = (bx & 63) * 16;
    int bh = b * 4 + w;
    int r0 = bx * 16;

    int r = l >> 2, cg = l & 3;          // score roles: row r, 16-entry chunk cg
    float sii = si[(size_t)bh * NN + n0 + r];
    const float* sjr = sj + (size_t)bh * NN;
    const unsigned* amrow = adjm + (size_t)(n0 + r) * 32;

    float lsum = 0.f;
    floatx4 acc[4] = { {0,0,0,0}, {0,0,0,0}, {0,0,0,0}, {0,0,0,0} };

    const __hip_bfloat16* Bsrc = WhT + (size_t)bh * 64 * NN;

    // stage tile 0: 8KB = 64 d x 64 m; inst k: row k*8 + (l>>3), col (l&7)*8
    short8 sreg[8], nreg[8];
    #pragma unroll
    for (int k = 0; k < 8; ++k)
        sreg[k] = *(const short8*)(Bsrc + (size_t)(k * 8 + (l >> 3)) * NN + (l & 7) * 8);

    #pragma unroll
    for (int it = 0; it < 16; ++it) {
        int m0 = it * 64;
        if (it < 15) {
            int m1 = m0 + 64;
            #pragma unroll
            for (int k = 0; k < 8; ++k)
                nreg[k] = *(const short8*)(Bsrc + (size_t)(k * 8 + (l >> 3)) * NN + m1 + (l & 7) * 8);
        }
        // ---- scores for this wave's 16 rows x 64 m (16 entries/lane) ----
        {
            int mb = m0 + cg * 16;
            unsigned bits = amrow[(m0 >> 5) + (cg >> 1)] >> ((cg & 1) * 16);
            #pragma unroll
            for (int c4 = 0; c4 < 4; ++c4) {
                floatx4 s4 = *(const floatx4*)(sjr + mb + c4 * 4);
                float pv[4];
                #pragma unroll
                for (int k = 0; k < 4; ++k) {
                    float x = sii + s4[k];
                    x = fmaxf(x, 0.2f * x);                               // leaky (prescaled)
                    x = ((bits >> (c4 * 4 + k)) & 1u) ? x : -1e9f;        // mask -> exp2 = 0
                    pv[k] = exp2f(x);
                    lsum += pv[k];
                }
                intx2 two;
                two[0] = (int)pk2(pv[0], pv[1]);
                two[1] = (int)pk2(pv[2], pv[3]);
                *(intx2*)(&pl[w][r][cg * 16 + c4 * 4]) = two;
            }
        }
        // ---- ds_write B tile (waits only on sreg's loads; nreg stays in flight) ----
        #pragma unroll
        for (int k = 0; k < 8; ++k)
            *(short8*)(&bst[w][k * 8 + (l >> 3)][(l & 7) * 8]) = sreg[k];
        // ---- MFMA: A = p rows, B = d-slices; 4 dt x 2 ks ----
        #pragma unroll
        for (int ks = 0; ks < 2; ++ks) {
            short8 afr = *(const short8*)(&pl[w][rl][q * 8 + ks * 32]);
            #pragma unroll
            for (int dt = 0; dt < 4; ++dt) {
                short8 bfr = *(const short8*)(&bst[w][dt * 16 + rl][q * 8 + ks * 32]);
                acc[dt] = __builtin_amdgcn_mfma_f32_16x16x32_bf16(afr, bfr, acc[dt], 0, 0, 0);
            }
        }
        #pragma unroll
        for (int z = 0; z < 8; ++z) sreg[z] = nreg[z];
    }

    // softmax denominators: reduce over 4 lanes sharing row r (same-wave)
    lsum += __shfl_xor(lsum, 1, 64);
    lsum += __shfl_xor(lsum, 2, 64);
    if (cg == 0) rinvs[w][r] = 1.f / lsum;
    float riv[4];
    #pragma unroll
    for (int i = 0; i < 4; ++i) riv[i] = rinvs[w][q * 4 + i];

    // prefetch proj B tile j=0 (in flight across the barriers)
    short8 psreg[8], pnreg[8];
    {
        const __hip_bfloat16* src = pwb + (size_t)w * 16 * 256;
        #pragma unroll
        for (int k = 0; k < 8; ++k) psreg[k] = *(const short8*)(src + k * 512 + l * 8);
    }

    __syncthreads();    // all waves done reading pl/bst; hm may overwrite pl region
    #pragma unroll
    for (int dt = 0; dt < 4; ++dt) {
        #pragma unroll
        for (int i = 0; i < 4; ++i) {
            unsigned uv = (__float_as_uint(acc[dt][i] * riv[i]) + 0x8000u) >> 16;
            hm[q * 4 + i][w * 64 + dt * 16 + rl] = __ushort_as_bfloat16((unsigned short)uv);
        }
    }
    __syncthreads();    // hm complete (all heads); attn bst dead -> pbst may reuse

    // ---- proj: A from hm, B streamed via wave-private pbst; wave w tiles ct = w + 4j ----
    short8 paf[8];
    #pragma unroll
    for (int k0 = 0; k0 < 8; ++k0) paf[k0] = *(const short8*)(&hm[rl][q * 8 + k0 * 32]);

    floatx4 pacc[4];
    #pragma unroll
    for (int j = 0; j < 4; ++j) {
        if (j < 3) {
            const __hip_bfloat16* src = pwb + (size_t)(w + 4 * (j + 1)) * 16 * 256;
            #pragma unroll
            for (int k = 0; k < 8; ++k) pnreg[k] = *(const short8*)(src + k * 512 + l * 8);
        }
        #pragma unroll
        for (int k = 0; k < 8; ++k)
            *(short8*)(&pbst[w][k * 2 + (l >> 5)][(l & 31) * 8]) = psreg[k];
        floatx4 a = {0.f, 0.f, 0.f, 0.f};
        #pragma unroll
        for (int k0 = 0; k0 < 8; ++k0) {
            short8 bf = *(const short8*)(&pbst[w][rl][q * 8 + k0 * 32]);
            a = __builtin_amdgcn_mfma_f32_16x16x32_bf16(paf[k0], bf, a, 0, 0, 0);
        }
        pacc[j] = a;
        #pragma unroll
        for (int z = 0; z < 8; ++z) psreg[z] = pnreg[z];
    }

    // bias + residual + LayerNorm
    float ps[4] = {0.f, 0.f, 0.f, 0.f};
    #pragma unroll
    for (int j = 0; j < 4; ++j) {
        int col = (w + j * 4) * 16 + rl;
        float pb = proj_b[col];
        #pragma unroll
        for (int i = 0; i < 4; ++i) {
            float v = pacc[j][i] + pb + h[(size_t)(r0 + q * 4 + i) * 256 + col];
            pacc[j][i] = v;
            ps[i] += v;
        }
    }
    #pragma unroll
    for (int i = 0; i < 4; ++i) {
        float s = ps[i];
        #pragma unroll
        for (int off = 1; off < 16; off <<= 1) s += __shfl_xor(s, off, 64);
        ps[i] = s;
    }
    if (rl == 0) {
        for (int i = 0; i < 4; ++i) red[0][w][q * 4 + i] = ps[i];
    }
    __syncthreads();
    float mu[4];
    #pragma unroll
    for (int i = 0; i < 4; ++i) {
        int row = q * 4 + i;
        mu[i] = (red[0][0][row] + red[0][1][row] + red[0][2][row] + red[0][3][row]) * (1.f / 256.f);
    }
    float vs[4] = {0.f, 0.f, 0.f, 0.f};
    #pragma unroll
    for (int j = 0; j < 4; ++j) {
        #pragma unroll
        for (int i = 0; i < 4; ++i) { float cv = pacc[j][i] - mu[i]; vs[i] += cv * cv; }
    }
    #pragma unroll
    for (int i = 0; i < 4; ++i) {
        float s = vs[i];
        #pragma unroll
        for (int off = 1; off < 16; off <<= 1) s += __shfl_xor(s, off, 64);
        vs[i] = s;
    }
    if (rl == 0) {
        for (int i = 0; i < 4; ++i) red[1][w][q * 4 + i] = vs[i];
    }
    __syncthreads();
    float rs[4];
    #pragma unroll
    for (int i = 0; i < 4; ++i) {
        int row = q * 4 + i;
        float var = (red[1][0][row] + red[1][1][row] + red[1][2][row] + red[1][3][row]) * (1.f / 256.f);
        rs[i] = rsqrtf(var + 1e-5f);
    }
    #pragma unroll
    for (int j = 0; j < 4; ++j) {
        int col = (w + j * 4) * 16 + rl;
        float g = gamma[col], be = beta[col];
        #pragma unroll
        for (int i = 0; i < 4; ++i)
            out[(size_t)(r0 + q * 4 + i) * 256 + col] = (pacc[j][i] - mu[i]) * rs[i] * g + be;
    }
}

extern "C" void kernel_launch(void* const* d_in, const int* in_sizes, int n_in,
                              void* d_out, int out_size, void* d_ws, size_t ws_size,
                              hipStream_t stream) {
    const float* h      = (const float*)d_in[0];
    const int*   adj    = (const int*)d_in[1];
    const float* W      = (const float*)d_in[2];
    const float* a1     = (const float*)d_in[3];
    const float* a2     = (const float*)d_in[4];
    const float* proj_w = (const float*)d_in[5];
    const float* proj_b = (const float*)d_in[6];
    const float* gamma  = (const float*)d_in[7];
    const float* beta   = (const float*)d_in[8];
    float* out = (float*)d_out;

    char* ws = (char*)d_ws;
    __hip_bfloat16* WhT = (__hip_bfloat16*)ws;   ws += (size_t)32 * 64 * NN * 2;   // 4 MB
    __hip_bfloat16* WTb = (__hip_bfloat16*)ws;   ws += 256 * 256 * 2;              // 128 KB
    __hip_bfloat16* pwb = (__hip_bfloat16*)ws;   ws += 256 * 256 * 2;              // 128 KB
    float* si = (float*)ws;                      ws += (size_t)32 * NN * 4;        // 128 KB
    float* sj = (float*)ws;                      ws += (size_t)32 * NN * 4;        // 128 KB
    unsigned* adjm = (unsigned*)ws;              ws += (size_t)NN * 32 * 4;        // 128 KB

    prep_kernel<<<160, 256, 0, stream>>>(W, proj_w, adj, WTb, pwb, adjm);
    wh_kernel<<<512, 256, 0, stream>>>(h, WTb, a1, a2, WhT, si, sj);
    attn_proj_kernel<<<512, 256, 0, stream>>>(adjm, WhT, si, sj, pwb, h, proj_b, gamma, beta, out);
}

// Round 15
// 120.864 us; speedup vs baseline: 1.4012x; 1.0100x over previous
//
#include <hip/hip_runtime.h>
#include <hip/hip_bf16.h>

#define NN 1024
#define LOG2E 1.44269504088896f

typedef __attribute__((ext_vector_type(8))) short short8;
typedef __attribute__((ext_vector_type(4))) float floatx4;
typedef __attribute__((ext_vector_type(4))) int intx4;
typedef __attribute__((ext_vector_type(2))) int intx2;

// fast f32->bf16 (round-half-up) pack of two floats into one dword
static __device__ __forceinline__ unsigned pk2(float f0, float f1) {
    unsigned u0 = __float_as_uint(f0) + 0x8000u;
    unsigned u1 = __float_as_uint(f1) + 0x8000u;
    return __builtin_amdgcn_perm(u1, u0, 0x07060302u);   // [u1.hi16 : u0.hi16]
}
static __device__ __forceinline__ short8 pk8(floatx4 v0, floatx4 v1) {
    union { intx4 i; short8 s; } u;
    u.i[0] = (int)pk2(v0[0], v0[1]); u.i[1] = (int)pk2(v0[2], v0[3]);
    u.i[2] = (int)pk2(v1[0], v1[1]); u.i[3] = (int)pk2(v1[2], v1[3]);
    return u.s;
}
// async global->LDS, 16B/lane, dest = ldsbase + lane*16
static __device__ __forceinline__ void load_lds16(const void* gsrc, void* lds) {
    __builtin_amdgcn_global_load_lds(
        (const __attribute__((address_space(1))) void*)gsrc,
        (__attribute__((address_space(3))) void*)lds, 16, 0, 0);
}

// ================= K0: prep — WTb transpose, pwb cast, adj bitmask =================
__global__ __launch_bounds__(256) void prep_kernel(
    const float* __restrict__ W, const float* __restrict__ proj_w,
    const int* __restrict__ adj,
    __hip_bfloat16* __restrict__ WTb,    // [256 o][256 k], o = hh*64+d
    __hip_bfloat16* __restrict__ pwb,    // [256 o][256 k]
    unsigned* __restrict__ adjm)         // [1024][32]
{
    int blk = blockIdx.x, t = threadIdx.x;
    if (blk < 16) {
        int o = blk * 16 + (t >> 4);
        int hh = o >> 6, d = o & 63;
        #pragma unroll
        for (int kk = 0; kk < 16; ++kk) {
            int k = (t & 15) + 16 * kk;
            WTb[(size_t)o * 256 + k] = __float2bfloat16(W[((size_t)hh * 256 + k) * 64 + d]);
        }
    } else if (blk < 32) {
        size_t base = (size_t)(blk - 16) * 4096 + (size_t)t * 16;
        #pragma unroll
        for (int k = 0; k < 16; k += 8) {
            floatx4 v0 = *(const floatx4*)(proj_w + base + k);
            floatx4 v1 = *(const floatx4*)(proj_w + base + k + 4);
            *(short8*)(pwb + base + k) = pk8(v0, v1);
        }
    } else {
        int n = (blk - 32) * 8 + (t >> 5);
        int wd = t & 31;
        const int* arow = adj + (size_t)n * NN + wd * 32;
        unsigned bits = 0;
        #pragma unroll
        for (int j4 = 0; j4 < 8; ++j4) {
            intx4 v = *(const intx4*)(arow + j4 * 4);
            #pragma unroll
            for (int j = 0; j < 4; ++j) if (v[j] != 0) bits |= (1u << (j4 * 4 + j));
        }
        adjm[(size_t)n * 32 + wd] = bits;
    }
}

// ================= K1: Wh GEMM — async LDS staging (swizzled, dbuf, wave-private) =================
// grid = 512 x 256t (4 waves). Wave w = d-slice w; tile j = head j (ct = w + 4j).
__global__ __launch_bounds__(256) void wh_kernel(
    const float* __restrict__ h,
    const __hip_bfloat16* __restrict__ WTb,
    const float* __restrict__ a1, const float* __restrict__ a2,
    __hip_bfloat16* __restrict__ WhT,   // [B*H][64][NN]
    float* __restrict__ si, float* __restrict__ sj)   // PRESCALED by log2e
{
    int t = threadIdx.x;
    int w = t >> 6, l = t & 63;
    int rl = l & 15, q = l >> 4;
    int r0 = blockIdx.x * 16;
    int bb = r0 >> 10, n0 = r0 & 1023;

    // wave-private double-buffered B tile: 16 rows x 256 k, UNPADDED, XOR-swizzled
    __shared__ __align__(16) __hip_bfloat16 bst[4][2][4096];
    __shared__ float redsi[4][4][16];
    __shared__ float redsj[4][4][16];

    // A-frags from h (f32 -> bf16 pack)
    short8 af[8];
    const float* Arow = h + (size_t)(r0 + rl) * 256 + q * 8;
    #pragma unroll
    for (int k0 = 0; k0 < 8; ++k0) {
        floatx4 v0 = *(const floatx4*)(Arow + k0 * 32);
        floatx4 v1 = *(const floatx4*)(Arow + k0 * 32 + 4);
        af[k0] = pk8(v0, v1);
    }

    // stage tile j=0 (ct = w): inst k covers rows k*2+(l>>5); swizzle g = (l&31) ^ (row&7)
    #pragma unroll
    for (int k = 0; k < 8; ++k) {
        int row = k * 2 + (l >> 5);
        int g = (l & 31) ^ (row & 7);
        load_lds16(WTb + (size_t)w * 4096 + row * 256 + g * 8, &bst[w][0][k * 512]);
    }

    #pragma unroll
    for (int j = 0; j < 4; ++j) {       // ct = w + 4j -> head j, d-slice w
        int cur = j & 1;
        if (j < 3) {
            int ctn = w + 4 * (j + 1);
            #pragma unroll
            for (int k = 0; k < 8; ++k) {
                int row = k * 2 + (l >> 5);
                int g = (l & 31) ^ (row & 7);
                load_lds16(WTb + (size_t)ctn * 4096 + row * 256 + g * 8, &bst[w][cur ^ 1][k * 512]);
            }
        }
        floatx4 acc = {0.f, 0.f, 0.f, 0.f};
        #pragma unroll
        for (int k0 = 0; k0 < 8; ++k0) {
            int p = ((k0 << 2) + q) ^ (rl & 7);
            short8 bf = *(const short8*)(&bst[w][cur][rl * 256 + p * 8]);
            acc = __builtin_amdgcn_mfma_f32_16x16x32_bf16(af[k0], bf, acc, 0, 0, 0);
        }

        // WhT[bh = bb*4+j][d = w*16+rl][n = n0+q*4 ..]
        intx2 pr;
        pr[0] = (int)pk2(acc[0], acc[1]);
        pr[1] = (int)pk2(acc[2], acc[3]);
        *(intx2*)(WhT + ((size_t)(bb * 4 + j) * 64 + w * 16 + rl) * NN + n0 + q * 4) = pr;

        // si/sj partials (prescaled by log2e), reduce over this wave's 16 d's
        float av1 = a1[j * 64 + w * 16 + rl] * LOG2E;
        float av2 = a2[j * 64 + w * 16 + rl] * LOG2E;
        #pragma unroll
        for (int i = 0; i < 4; ++i) {
            float p1 = acc[i] * av1, p2 = acc[i] * av2;
            #pragma unroll
            for (int off = 1; off < 16; off <<= 1) {
                p1 += __shfl_xor(p1, off, 64);
                p2 += __shfl_xor(p2, off, 64);
            }
            if (rl == 0) { redsi[w][j][q * 4 + i] = p1; redsj[w][j][q * 4 + i] = p2; }
        }
    }
    __syncthreads();

    if (t < 64) {
        int head = t >> 4, row = t & 15;
        si[(size_t)(bb * 4 + head) * NN + n0 + row] =
            redsi[0][head][row] + redsi[1][head][row] + redsi[2][head][row] + redsi[3][head][row];
    } else if (t < 128) {
        int u = t - 64;
        int head = u >> 4, row = u & 15;
        sj[(size_t)(bb * 4 + head) * NN + n0 + row] =
            redsj[0][head][row] + redsj[1][head][row] + redsj[2][head][row] + redsj[3][head][row];
    }
}

// ================= K2: attn (async swizzled dbuf staging) + proj + LN fused =================
// grid = 512 x 256t. Block = (b, 16-token tile); wave w = head w in attn phase.
// LDS (75264 B): [attn] bst 4x2x8192 @0 | pl 4x16x72 @65536 | rinvs @74752
//                [proj] pbst 4x16x264 @0 | hm 16x264 @65536 | red @74752
__global__ __launch_bounds__(256) void attn_proj_kernel(
    const unsigned* __restrict__ adjm,
    const __hip_bfloat16* __restrict__ WhT,
    const float* __restrict__ si, const float* __restrict__ sj,
    const __hip_bfloat16* __restrict__ pwb,
    const float* __restrict__ h,
    const float* __restrict__ proj_b, const float* __restrict__ gamma,
    const float* __restrict__ beta,
    float* __restrict__ out)
{
    __shared__ __align__(16) char smem[75264];
    auto bst   = reinterpret_cast<__hip_bfloat16 (*)[2][8192 / 2]>(smem);     // [4][2][4096]
    auto pl    = reinterpret_cast<__hip_bfloat16 (*)[16][72]>(smem + 65536);
    auto rinvs = reinterpret_cast<float (*)[16]>(smem + 74752);
    auto pbst  = reinterpret_cast<__hip_bfloat16 (*)[16][264]>(smem);         // proj overlay
    auto hm    = reinterpret_cast<__hip_bfloat16 (*)[264]>(smem + 65536);
    auto red   = reinterpret_cast<float (*)[4][16]>(smem + 74752);

    int bx = blockIdx.x, t = threadIdx.x;
    int w = t >> 6, l = t & 63;
    int rl = l & 15, q = l >> 4;
    int b = bx >> 6, n0 = (bx & 63) * 16;
    int bh = b * 4 + w;
    int r0 = bx * 16;

    int r = l >> 2, cg = l & 3;          // score roles: row r, 16-entry chunk cg
    float sii = si[(size_t)bh * NN + n0 + r];
    const float* sjr = sj + (size_t)bh * NN;
    const unsigned* amrow = adjm + (size_t)(n0 + r) * 32;

    float lsum = 0.f;
    floatx4 acc[4] = { {0,0,0,0}, {0,0,0,0}, {0,0,0,0}, {0,0,0,0} };

    const __hip_bfloat16* Bhead = WhT + (size_t)bh * 64 * NN;
    int lrow = l >> 3;                   // 0..7
    int lgrp = (l & 7) ^ lrow;           // XOR swizzle group (row&7 == lrow)

    // stage tile 0 into buf0: 64 d x 64 m; inst k covers rows k*8+lrow
    #pragma unroll
    for (int k = 0; k < 8; ++k)
        load_lds16(Bhead + (size_t)(k * 8 + lrow) * NN + lgrp * 8, &bst[w][0][k * 512]);

    #pragma unroll
    for (int it = 0; it < 16; ++it) {
        int m0 = it * 64;
        int cur = it & 1;
        if (it < 15) {
            int m1 = m0 + 64;
            #pragma unroll
            for (int k = 0; k < 8; ++k)
                load_lds16(Bhead + (size_t)(k * 8 + lrow) * NN + m1 + lgrp * 8,
                           &bst[w][cur ^ 1][k * 512]);
        }
        // ---- scores for this wave's 16 rows x 64 m (16 entries/lane) ----
        {
            int mb = m0 + cg * 16;
            unsigned bits = amrow[(m0 >> 5) + (cg >> 1)] >> ((cg & 1) * 16);
            #pragma unroll
            for (int c4 = 0; c4 < 4; ++c4) {
                floatx4 s4 = *(const floatx4*)(sjr + mb + c4 * 4);
                float pv[4];
                #pragma unroll
                for (int k = 0; k < 4; ++k) {
                    float x = sii + s4[k];
                    x = fmaxf(x, 0.2f * x);                               // leaky (prescaled)
                    x = ((bits >> (c4 * 4 + k)) & 1u) ? x : -1e9f;        // mask -> exp2 = 0
                    pv[k] = exp2f(x);
                    lsum += pv[k];
                }
                intx2 two;
                two[0] = (int)pk2(pv[0], pv[1]);
                two[1] = (int)pk2(pv[2], pv[3]);
                *(intx2*)(&pl[w][r][cg * 16 + c4 * 4]) = two;
            }
        }
        // ---- MFMA: A = p rows (in-order DS per wave), B = swizzled bst ----
        #pragma unroll
        for (int ks = 0; ks < 2; ++ks) {
            short8 afr = *(const short8*)(&pl[w][rl][ks * 32 + q * 8]);
            #pragma unroll
            for (int dt = 0; dt < 4; ++dt) {
                int p = ((ks << 2) + q) ^ (rl & 7);
                short8 bfr = *(const short8*)(&bst[w][cur][(dt * 16 + rl) * 64 + p * 8]);
                acc[dt] = __builtin_amdgcn_mfma_f32_16x16x32_bf16(afr, bfr, acc[dt], 0, 0, 0);
            }
        }
    }

    // softmax denominators: reduce over 4 lanes sharing row r (same-wave)
    lsum += __shfl_xor(lsum, 1, 64);
    lsum += __shfl_xor(lsum, 2, 64);
    if (cg == 0) rinvs[w][r] = 1.f / lsum;
    float riv[4];
    #pragma unroll
    for (int i = 0; i < 4; ++i) riv[i] = rinvs[w][q * 4 + i];

    // prefetch proj B tile j=0 (stays in flight across the barriers)
    short8 psreg[8], pnreg[8];
    {
        const __hip_bfloat16* src = pwb + (size_t)w * 16 * 256;
        #pragma unroll
        for (int k = 0; k < 8; ++k) psreg[k] = *(const short8*)(src + k * 512 + l * 8);
    }

    __syncthreads();    // all waves done with pl/bst reads; hm may overwrite pl region
    #pragma unroll
    for (int dt = 0; dt < 4; ++dt) {
        #pragma unroll
        for (int i = 0; i < 4; ++i) {
            unsigned uv = (__float_as_uint(acc[dt][i] * riv[i]) + 0x8000u) >> 16;
            hm[q * 4 + i][w * 64 + dt * 16 + rl] = __ushort_as_bfloat16((unsigned short)uv);
        }
    }
    __syncthreads();    // hm complete; attn bst dead -> pbst may reuse

    // ---- proj: A from hm, B streamed via wave-private pbst; wave w tiles ct = w + 4j ----
    short8 paf[8];
    #pragma unroll
    for (int k0 = 0; k0 < 8; ++k0) paf[k0] = *(const short8*)(&hm[rl][q * 8 + k0 * 32]);

    floatx4 pacc[4];
    #pragma unroll
    for (int j = 0; j < 4; ++j) {
        if (j < 3) {
            const __hip_bfloat16* src = pwb + (size_t)(w + 4 * (j + 1)) * 16 * 256;
            #pragma unroll
            for (int k = 0; k < 8; ++k) pnreg[k] = *(const short8*)(src + k * 512 + l * 8);
        }
        #pragma unroll
        for (int k = 0; k < 8; ++k)
            *(short8*)(&pbst[w][k * 2 + (l >> 5)][(l & 31) * 8]) = psreg[k];
        floatx4 a = {0.f, 0.f, 0.f, 0.f};
        #pragma unroll
        for (int k0 = 0; k0 < 8; ++k0) {
            short8 bf = *(const short8*)(&pbst[w][rl][q * 8 + k0 * 32]);
            a = __builtin_amdgcn_mfma_f32_16x16x32_bf16(paf[k0], bf, a, 0, 0, 0);
        }
        pacc[j] = a;
        #pragma unroll
        for (int z = 0; z < 8; ++z) psreg[z] = pnreg[z];
    }

    // bias + residual + LayerNorm
    float ps[4] = {0.f, 0.f, 0.f, 0.f};
    #pragma unroll
    for (int j = 0; j < 4; ++j) {
        int col = (w + j * 4) * 16 + rl;
        float pb = proj_b[col];
        #pragma unroll
        for (int i = 0; i < 4; ++i) {
            float v = pacc[j][i] + pb + h[(size_t)(r0 + q * 4 + i) * 256 + col];
            pacc[j][i] = v;
            ps[i] += v;
        }
    }
    #pragma unroll
    for (int i = 0; i < 4; ++i) {
        float s = ps[i];
        #pragma unroll
        for (int off = 1; off < 16; off <<= 1) s += __shfl_xor(s, off, 64);
        ps[i] = s;
    }
    if (rl == 0) {
        for (int i = 0; i < 4; ++i) red[0][w][q * 4 + i] = ps[i];
    }
    __syncthreads();
    float mu[4];
    #pragma unroll
    for (int i = 0; i < 4; ++i) {
        int row = q * 4 + i;
        mu[i] = (red[0][0][row] + red[0][1][row] + red[0][2][row] + red[0][3][row]) * (1.f / 256.f);
    }
    float vs[4] = {0.f, 0.f, 0.f, 0.f};
    #pragma unroll
    for (int j = 0; j < 4; ++j) {
        #pragma unroll
        for (int i = 0; i < 4; ++i) { float cv = pacc[j][i] - mu[i]; vs[i] += cv * cv; }
    }
    #pragma unroll
    for (int i = 0; i < 4; ++i) {
        float s = vs[i];
        #pragma unroll
        for (int off = 1; off < 16; off <<= 1) s += __shfl_xor(s, off, 64);
        vs[i] = s;
    }
    if (rl == 0) {
        for (int i = 0; i < 4; ++i) red[1][w][q * 4 + i] = vs[i];
    }
    __syncthreads();
    float rs[4];
    #pragma unroll
    for (int i = 0; i < 4; ++i) {
        int row = q * 4 + i;
        float var = (red[1][0][row] + red[1][1][row] + red[1][2][row] + red[1][3][row]) * (1.f / 256.f);
        rs[i] = rsqrtf(var + 1e-5f);
    }
    #pragma unroll
    for (int j = 0; j < 4; ++j) {
        int col = (w + j * 4) * 16 + rl;
        float g = gamma[col], be = beta[col];
        #pragma unroll
        for (int i = 0; i < 4; ++i)
            out[(size_t)(r0 + q * 4 + i) * 256 + col] = (pacc[j][i] - mu[i]) * rs[i] * g + be;
    }
}

extern "C" void kernel_launch(void* const* d_in, const int* in_sizes, int n_in,
                              void* d_out, int out_size, void* d_ws, size_t ws_size,
                              hipStream_t stream) {
    const float* h      = (const float*)d_in[0];
    const int*   adj    = (const int*)d_in[1];
    const float* W      = (const float*)d_in[2];
    const float* a1     = (const float*)d_in[3];
    const float* a2     = (const float*)d_in[4];
    const float* proj_w = (const float*)d_in[5];
    const float* proj_b = (const float*)d_in[6];
    const float* gamma  = (const float*)d_in[7];
    const float* beta   = (const float*)d_in[8];
    float* out = (float*)d_out;

    char* ws = (char*)d_ws;
    __hip_bfloat16* WhT = (__hip_bfloat16*)ws;   ws += (size_t)32 * 64 * NN * 2;   // 4 MB
    __hip_bfloat16* WTb = (__hip_bfloat16*)ws;   ws += 256 * 256 * 2;              // 128 KB
    __hip_bfloat16* pwb = (__hip_bfloat16*)ws;   ws += 256 * 256 * 2;              // 128 KB
    float* si = (float*)ws;                      ws += (size_t)32 * NN * 4;        // 128 KB
    float* sj = (float*)ws;                      ws += (size_t)32 * NN * 4;        // 128 KB
    unsigned* adjm = (unsigned*)ws;              ws += (size_t)NN * 32 * 4;        // 128 KB

    prep_kernel<<<160, 256, 0, stream>>>(W, proj_w, adj, WTb, pwb, adjm);
    wh_kernel<<<512, 256, 0, stream>>>(h, WTb, a1, a2, WhT, si, sj);
    attn_proj_kernel<<<512, 256, 0, stream>>>(adjm, WhT, si, sj, pwb, h, proj_b, gamma, beta, out);
}

// Round 17
// 120.269 us; speedup vs baseline: 1.4081x; 1.0049x over previous
//
#include <hip/hip_runtime.h>
#include <hip/hip_bf16.h>

#define NN 1024
#define LOG2E 1.44269504088896f

typedef __attribute__((ext_vector_type(8))) short short8;
typedef __attribute__((ext_vector_type(4))) float floatx4;
typedef __attribute__((ext_vector_type(4))) int intx4;
typedef __attribute__((ext_vector_type(2))) int intx2;

#define WAIT_VM0()   asm volatile("s_waitcnt vmcnt(0)" ::: "memory")
#define WAIT_LGKM0() asm volatile("s_waitcnt lgkmcnt(0)" ::: "memory")

// fast f32->bf16 (round-half-up) pack of two floats into one dword
static __device__ __forceinline__ unsigned pk2(float f0, float f1) {
    unsigned u0 = __float_as_uint(f0) + 0x8000u;
    unsigned u1 = __float_as_uint(f1) + 0x8000u;
    return __builtin_amdgcn_perm(u1, u0, 0x07060302u);   // [u1.hi16 : u0.hi16]
}
static __device__ __forceinline__ short8 pk8(floatx4 v0, floatx4 v1) {
    union { intx4 i; short8 s; } u;
    u.i[0] = (int)pk2(v0[0], v0[1]); u.i[1] = (int)pk2(v0[2], v0[3]);
    u.i[2] = (int)pk2(v1[0], v1[1]); u.i[3] = (int)pk2(v1[2], v1[3]);
    return u.s;
}
// async global->LDS, 16B/lane, dest = ldsbase + lane*16
static __device__ __forceinline__ void load_lds16(const void* gsrc, void* lds) {
    __builtin_amdgcn_global_load_lds(
        (const __attribute__((address_space(1))) void*)gsrc,
        (__attribute__((address_space(3))) void*)lds, 16, 0, 0);
}

// ================= K0: prep — WTb transpose, pwb cast, adj bitmask =================
__global__ __launch_bounds__(256) void prep_kernel(
    const float* __restrict__ W, const float* __restrict__ proj_w,
    const int* __restrict__ adj,
    __hip_bfloat16* __restrict__ WTb,    // [256 o][256 k], o = hh*64+d
    __hip_bfloat16* __restrict__ pwb,    // [256 o][256 k]
    unsigned* __restrict__ adjm)         // [1024][32]
{
    int blk = blockIdx.x, t = threadIdx.x;
    if (blk < 16) {
        int o = blk * 16 + (t >> 4);
        int hh = o >> 6, d = o & 63;
        #pragma unroll
        for (int kk = 0; kk < 16; ++kk) {
            int k = (t & 15) + 16 * kk;
            WTb[(size_t)o * 256 + k] = __float2bfloat16(W[((size_t)hh * 256 + k) * 64 + d]);
        }
    } else if (blk < 32) {
        size_t base = (size_t)(blk - 16) * 4096 + (size_t)t * 16;
        #pragma unroll
        for (int k = 0; k < 16; k += 8) {
            floatx4 v0 = *(const floatx4*)(proj_w + base + k);
            floatx4 v1 = *(const floatx4*)(proj_w + base + k + 4);
            *(short8*)(pwb + base + k) = pk8(v0, v1);
        }
    } else {
        int n = (blk - 32) * 8 + (t >> 5);
        int wd = t & 31;
        const int* arow = adj + (size_t)n * NN + wd * 32;
        unsigned bits = 0;
        #pragma unroll
        for (int j4 = 0; j4 < 8; ++j4) {
            intx4 v = *(const intx4*)(arow + j4 * 4);
            #pragma unroll
            for (int j = 0; j < 4; ++j) if (v[j] != 0) bits |= (1u << (j4 * 4 + j));
        }
        adjm[(size_t)n * 32 + wd] = bits;
    }
}

// ================= K1: Wh GEMM — async single-buffer staging + explicit fences =================
// grid = 512 x 256t (4 waves). Wave w = d-slice w; tile j = head j (ct = w + 4j).
__global__ __launch_bounds__(256) void wh_kernel(
    const float* __restrict__ h,
    const __hip_bfloat16* __restrict__ WTb,
    const float* __restrict__ a1, const float* __restrict__ a2,
    __hip_bfloat16* __restrict__ WhT,   // [B*H][64][NN]
    float* __restrict__ si, float* __restrict__ sj)   // PRESCALED by log2e
{
    int t = threadIdx.x;
    int w = t >> 6, l = t & 63;
    int rl = l & 15, q = l >> 4;
    int r0 = blockIdx.x * 16;
    int bb = r0 >> 10, n0 = r0 & 1023;

    // wave-private single-buffer B tile: 16 rows x 256 k, UNPADDED, XOR-swizzled
    __shared__ __align__(16) __hip_bfloat16 bst[4][4096];
    __shared__ float redsi[4][4][16];
    __shared__ float redsj[4][4][16];

    // A-frags from h (f32 -> bf16 pack)
    short8 af[8];
    const float* Arow = h + (size_t)(r0 + rl) * 256 + q * 8;
    #pragma unroll
    for (int k0 = 0; k0 < 8; ++k0) {
        floatx4 v0 = *(const floatx4*)(Arow + k0 * 32);
        floatx4 v1 = *(const floatx4*)(Arow + k0 * 32 + 4);
        af[k0] = pk8(v0, v1);
    }

    // stage tile j=0 (ct = w): inst k covers rows k*2+(l>>5); swizzle g = (l&31) ^ (row&7)
    #pragma unroll
    for (int k = 0; k < 8; ++k) {
        int row = k * 2 + (l >> 5);
        int g = (l & 31) ^ (row & 7);
        load_lds16(WTb + (size_t)w * 4096 + row * 256 + g * 8, &bst[w][k * 512]);
    }

    #pragma unroll
    for (int j = 0; j < 4; ++j) {       // ct = w + 4j -> head j, d-slice w
        WAIT_VM0();                      // tile-j DMAs landed in LDS
        floatx4 acc = {0.f, 0.f, 0.f, 0.f};
        #pragma unroll
        for (int k0 = 0; k0 < 8; ++k0) {
            int p = ((k0 << 2) + q) ^ (rl & 7);
            short8 bf = *(const short8*)(&bst[w][rl * 256 + p * 8]);
            acc = __builtin_amdgcn_mfma_f32_16x16x32_bf16(af[k0], bf, acc, 0, 0, 0);
        }
        WAIT_LGKM0();                    // ds_reads retired to VGPRs; LDS may be overwritten
        if (j < 3) {                     // issue loads(j+1); epilogue below is the blanket
            int ctn = w + 4 * (j + 1);
            #pragma unroll
            for (int k = 0; k < 8; ++k) {
                int row = k * 2 + (l >> 5);
                int g = (l & 31) ^ (row & 7);
                load_lds16(WTb + (size_t)ctn * 4096 + row * 256 + g * 8, &bst[w][k * 512]);
            }
        }

        // WhT[bh = bb*4+j][d = w*16+rl][n = n0+q*4 ..]
        intx2 pr;
        pr[0] = (int)pk2(acc[0], acc[1]);
        pr[1] = (int)pk2(acc[2], acc[3]);
        *(intx2*)(WhT + ((size_t)(bb * 4 + j) * 64 + w * 16 + rl) * NN + n0 + q * 4) = pr;

        // si/sj partials (prescaled by log2e), reduce over this wave's 16 d's
        float av1 = a1[j * 64 + w * 16 + rl] * LOG2E;
        float av2 = a2[j * 64 + w * 16 + rl] * LOG2E;
        #pragma unroll
        for (int i = 0; i < 4; ++i) {
            float p1 = acc[i] * av1, p2 = acc[i] * av2;
            #pragma unroll
            for (int off = 1; off < 16; off <<= 1) {
                p1 += __shfl_xor(p1, off, 64);
                p2 += __shfl_xor(p2, off, 64);
            }
            if (rl == 0) { redsi[w][j][q * 4 + i] = p1; redsj[w][j][q * 4 + i] = p2; }
        }
    }
    __syncthreads();

    if (t < 64) {
        int head = t >> 4, row = t & 15;
        si[(size_t)(bb * 4 + head) * NN + n0 + row] =
            redsi[0][head][row] + redsi[1][head][row] + redsi[2][head][row] + redsi[3][head][row];
    } else if (t < 128) {
        int u = t - 64;
        int head = u >> 4, row = u & 15;
        sj[(size_t)(bb * 4 + head) * NN + n0 + row] =
            redsj[0][head][row] + redsj[1][head][row] + redsj[2][head][row] + redsj[3][head][row];
    }
}

// ================= K2: attn (async single-buffer + fences) + proj + LN fused =================
// grid = 512 x 256t. Block = (b, 16-token tile); wave w = head w in attn phase.
// LDS (42752 B): [attn] bst 4x4096 @0 | pl 4x16x72 @32768 | rinvs @41984 | red @42240
//                [proj] pbst 4x4096 @0 (swizzled) | hm 16x264 @32768
__global__ __launch_bounds__(256) void attn_proj_kernel(
    const unsigned* __restrict__ adjm,
    const __hip_bfloat16* __restrict__ WhT,
    const float* __restrict__ si, const float* __restrict__ sj,
    const __hip_bfloat16* __restrict__ pwb,
    const float* __restrict__ h,
    const float* __restrict__ proj_b, const float* __restrict__ gamma,
    const float* __restrict__ beta,
    float* __restrict__ out)
{
    __shared__ __align__(16) char smem[42752];
    auto bst   = reinterpret_cast<__hip_bfloat16 (*)[4096]>(smem);            // attn B tiles (per wave)
    auto pl    = reinterpret_cast<__hip_bfloat16 (*)[16][72]>(smem + 32768);
    auto rinvs = reinterpret_cast<float (*)[16]>(smem + 41984);
    auto pbst  = reinterpret_cast<__hip_bfloat16 (*)[4096]>(smem);            // proj overlay (same per-wave region)
    auto hm    = reinterpret_cast<__hip_bfloat16 (*)[264]>(smem + 32768);
    auto red   = reinterpret_cast<float (*)[4][16]>(smem + 42240);

    int bx = blockIdx.x, t = threadIdx.x;
    int w = t >> 6, l = t & 63;
    int rl = l & 15, q = l >> 4;
    int b = bx >> 6, n0 = (bx & 63) * 16;
    int bh = b * 4 + w;
    int r0 = bx * 16;

    int r = l >> 2, cg = l & 3;          // score roles: row r, 16-entry chunk cg
    float sii = si[(size_t)bh * NN + n0 + r];
    const float* sjr = sj + (size_t)bh * NN;
    const unsigned* amrow = adjm + (size_t)(n0 + r) * 32;

    float lsum = 0.f;
    floatx4 acc[4] = { {0,0,0,0}, {0,0,0,0}, {0,0,0,0}, {0,0,0,0} };

    const __hip_bfloat16* Bhead = WhT + (size_t)bh * 64 * NN;
    int lrow = l >> 3;                   // 0..7
    int lgrp = (l & 7) ^ lrow;           // XOR swizzle group (row&7 == lrow)

    for (int it = 0; it < 16; ++it) {
        int m0 = it * 64;
        // issue loads(it): only these are outstanding at the fence below
        #pragma unroll
        for (int k = 0; k < 8; ++k)
            load_lds16(Bhead + (size_t)(k * 8 + lrow) * NN + m0 + lgrp * 8, &bst[w][k * 512]);
        // ---- scores(it): VALU blanket over the staging latency ----
        {
            int mb = m0 + cg * 16;
            unsigned bits = amrow[(m0 >> 5) + (cg >> 1)] >> ((cg & 1) * 16);
            #pragma unroll
            for (int c4 = 0; c4 < 4; ++c4) {
                floatx4 s4 = *(const floatx4*)(sjr + mb + c4 * 4);
                float pv[4];
                #pragma unroll
                for (int k = 0; k < 4; ++k) {
                    float x = sii + s4[k];
                    x = fmaxf(x, 0.2f * x);                               // leaky (prescaled)
                    x = ((bits >> (c4 * 4 + k)) & 1u) ? x : -1e9f;        // mask -> exp2 = 0
                    pv[k] = exp2f(x);
                    lsum += pv[k];
                }
                intx2 two;
                two[0] = (int)pk2(pv[0], pv[1]);
                two[1] = (int)pk2(pv[2], pv[3]);
                *(intx2*)(&pl[w][r][cg * 16 + c4 * 4]) = two;
            }
        }
        WAIT_VM0();                      // tile-it DMAs landed in LDS
        // ---- MFMA(it): A = p rows (in-order DS per wave), B = swizzled bst ----
        #pragma unroll
        for (int ks = 0; ks < 2; ++ks) {
            short8 afr = *(const short8*)(&pl[w][rl][ks * 32 + q * 8]);
            #pragma unroll
            for (int dt = 0; dt < 4; ++dt) {
                int p = ((ks << 2) + q) ^ (rl & 7);
                short8 bfr = *(const short8*)(&bst[w][(dt * 16 + rl) * 64 + p * 8]);
                acc[dt] = __builtin_amdgcn_mfma_f32_16x16x32_bf16(afr, bfr, acc[dt], 0, 0, 0);
            }
        }
        WAIT_LGKM0();                    // ds_reads retired; next iteration may overwrite bst
    }

    // softmax denominators: reduce over 4 lanes sharing row r (same-wave)
    lsum += __shfl_xor(lsum, 1, 64);
    lsum += __shfl_xor(lsum, 2, 64);
    if (cg == 0) rinvs[w][r] = 1.f / lsum;
    float riv[4];
    #pragma unroll
    for (int i = 0; i < 4; ++i) riv[i] = rinvs[w][q * 4 + i];

    // issue proj B tile j=0 into this wave's (now dead) bst region — in flight across barriers
    #pragma unroll
    for (int k = 0; k < 8; ++k) {
        int row = k * 2 + (l >> 5);
        int g = (l & 31) ^ (row & 7);
        load_lds16(pwb + (size_t)w * 4096 + row * 256 + g * 8, &pbst[w][k * 512]);
    }

    __syncthreads();    // all waves done with pl reads; hm may overwrite pl region
    #pragma unroll
    for (int dt = 0; dt < 4; ++dt) {
        #pragma unroll
        for (int i = 0; i < 4; ++i) {
            unsigned uv = (__float_as_uint(acc[dt][i] * riv[i]) + 0x8000u) >> 16;
            hm[q * 4 + i][w * 64 + dt * 16 + rl] = __ushort_as_bfloat16((unsigned short)uv);
        }
    }
    __syncthreads();    // hm complete (all heads)

    // ---- proj: A from hm, B async-staged via wave-private pbst; wave w tiles ct = w + 4j ----
    short8 paf[8];
    #pragma unroll
    for (int k0 = 0; k0 < 8; ++k0) paf[k0] = *(const short8*)(&hm[rl][q * 8 + k0 * 32]);

    floatx4 pacc[4];
    #pragma unroll
    for (int j = 0; j < 4; ++j) {
        WAIT_VM0();                      // tile-j DMAs landed
        floatx4 a = {0.f, 0.f, 0.f, 0.f};
        #pragma unroll
        for (int k0 = 0; k0 < 8; ++k0) {
            int p = ((k0 << 2) + q) ^ (rl & 7);
            short8 bf = *(const short8*)(&pbst[w][rl * 256 + p * 8]);
            a = __builtin_amdgcn_mfma_f32_16x16x32_bf16(paf[k0], bf, a, 0, 0, 0);
        }
        pacc[j] = a;
        WAIT_LGKM0();                    // ds_reads retired; safe to overwrite
        if (j < 3) {
            int ctn = w + 4 * (j + 1);
            #pragma unroll
            for (int k = 0; k < 8; ++k) {
                int row = k * 2 + (l >> 5);
                int g = (l & 31) ^ (row & 7);
                load_lds16(pwb + (size_t)ctn * 4096 + row * 256 + g * 8, &pbst[w][k * 512]);
            }
        }
    }

    // bias + residual + LayerNorm
    float ps[4] = {0.f, 0.f, 0.f, 0.f};
    #pragma unroll
    for (int j = 0; j < 4; ++j) {
        int col = (w + j * 4) * 16 + rl;
        float pb = proj_b[col];
        #pragma unroll
        for (int i = 0; i < 4; ++i) {
            float v = pacc[j][i] + pb + h[(size_t)(r0 + q * 4 + i) * 256 + col];
            pacc[j][i] = v;
            ps[i] += v;
        }
    }
    #pragma unroll
    for (int i = 0; i < 4; ++i) {
        float s = ps[i];
        #pragma unroll
        for (int off = 1; off < 16; off <<= 1) s += __shfl_xor(s, off, 64);
        ps[i] = s;
    }
    if (rl == 0) {
        for (int i = 0; i < 4; ++i) red[0][w][q * 4 + i] = ps[i];
    }
    __syncthreads();
    float mu[4];
    #pragma unroll
    for (int i = 0; i < 4; ++i) {
        int row = q * 4 + i;
        mu[i] = (red[0][0][row] + red[0][1][row] + red[0][2][row] + red[0][3][row]) * (1.f / 256.f);
    }
    float vs[4] = {0.f, 0.f, 0.f, 0.f};
    #pragma unroll
    for (int j = 0; j < 4; ++j) {
        #pragma unroll
        for (int i = 0; i < 4; ++i) { float cv = pacc[j][i] - mu[i]; vs[i] += cv * cv; }
    }
    #pragma unroll
    for (int i = 0; i < 4; ++i) {
        float s = vs[i];
        #pragma unroll
        for (int off = 1; off < 16; off <<= 1) s += __shfl_xor(s, off, 64);
        vs[i] = s;
    }
    if (rl == 0) {
        for (int i = 0; i < 4; ++i) red[1][w][q * 4 + i] = vs[i];
    }
    __syncthreads();
    float rs[4];
    #pragma unroll
    for (int i = 0; i < 4; ++i) {
        int row = q * 4 + i;
        float var = (red[1][0][row] + red[1][1][row] + red[1][2][row] + red[1][3][row]) * (1.f / 256.f);
        rs[i] = rsqrtf(var + 1e-5f);
    }
    #pragma unroll
    for (int j = 0; j < 4; ++j) {
        int col = (w + j * 4) * 16 + rl;
        float g = gamma[col], be = beta[col];
        #pragma unroll
        for (int i = 0; i < 4; ++i)
            out[(size_t)(r0 + q * 4 + i) * 256 + col] = (pacc[j][i] - mu[i]) * rs[i] * g + be;
    }
}

extern "C" void kernel_launch(void* const* d_in, const int* in_sizes, int n_in,
                              void* d_out, int out_size, void* d_ws, size_t ws_size,
                              hipStream_t stream) {
    const float* h      = (const float*)d_in[0];
    const int*   adj    = (const int*)d_in[1];
    const float* W      = (const float*)d_in[2];
    const float* a1     = (const float*)d_in[3];
    const float* a2     = (const float*)d_in[4];
    const float* proj_w = (const float*)d_in[5];
    const float* proj_b = (const float*)d_in[6];
    const float* gamma  = (const float*)d_in[7];
    const float* beta   = (const float*)d_in[8];
    float* out = (float*)d_out;

    char* ws = (char*)d_ws;
    __hip_bfloat16* WhT = (__hip_bfloat16*)ws;   ws += (size_t)32 * 64 * NN * 2;   // 4 MB
    __hip_bfloat16* WTb = (__hip_bfloat16*)ws;   ws += 256 * 256 * 2;              // 128 KB
    __hip_bfloat16* pwb = (__hip_bfloat16*)ws;   ws += 256 * 256 * 2;              // 128 KB
    float* si = (float*)ws;                      ws += (size_t)32 * NN * 4;        // 128 KB
    float* sj = (float*)ws;                      ws += (size_t)32 * NN * 4;        // 128 KB
    unsigned* adjm = (unsigned*)ws;              ws += (size_t)NN * 32 * 4;        // 128 KB

    prep_kernel<<<160, 256, 0, stream>>>(W, proj_w, adj, WTb, pwb, adjm);
    wh_kernel<<<512, 256, 0, stream>>>(h, WTb, a1, a2, WhT, si, sj);
    attn_proj_kernel<<<512, 256, 0, stream>>>(adjm, WhT, si, sj, pwb, h, proj_b, gamma, beta, out);
}